// Round 1
// baseline (618.785 us; speedup 1.0000x reference)
//
#include <hip/hip_runtime.h>
#include <math.h>

// PathPreservingNetwork — factored-class implementation.
//
// Structure: every path value is s * C[class], s in {-1,0,+1}. Class counts per
// layer input: 1,1,3,7,15,31 (D' = 2D+1; class 0 = zero-path child tanh(b),
// class 1+2u = tanh(b - Y[u]), class 2+2u = tanh(b + Y[u])).
// GEMMs therefore run on B*D rows instead of B*P rows: 11.4 GF total vs 49.6 GF.
//
// Prune semantics (jax.lax.top_k stable, lower index first on ties) are
// reproduced exactly: per-class norms computed once -> duplicate/± paths get
// bitwise-identical keys; rank = #{e': key'>key || (key'==key && e'<e)}.

#define K_DIM 1024

// ---------------------------------------------------------------- GEMM ------
// A: (rows = B*D, K=1024) row-major. W: (1024, N) row-major.
// MODE 0: layer 0      -> out row (b*Dn+0)      = tanh(bias + acc)
// MODE 1: layers 1..4  -> out rows (b*Dn+1+2u) = tanh(bias - acc),
//                                  (b*Dn+2+2u) = tanh(bias + acc)
// MODE 2: layer 5      -> out row r = acc (raw, no bias)
template <int MODE>
__global__ void __launch_bounds__(256)
gemm_cls(const float* __restrict__ A, const float* __restrict__ W,
         const float* __restrict__ bias, float* __restrict__ out,
         int D, int Dn, int N) {
  __shared__ float As[16][65];  // [k][m], +1 pad breaks write conflicts
  __shared__ float Bs[16][64];  // [k][n]
  const int t = threadIdx.x;
  const int tx = t & 15, ty = t >> 4;
  const int tx4 = tx * 4, ty4 = ty * 4;
  const int row0 = blockIdx.y * 64;
  const int col0 = blockIdx.x * 64;
  const int lm = t >> 2;          // A-tile row 0..63
  const int lk = (t & 3) << 2;    // A-tile k offset 0,4,8,12
  const int bk = t >> 4;          // B-tile k row 0..15
  const int bn = (t & 15) << 2;   // B-tile col offset
  const float* Ap = A + (size_t)(row0 + lm) * K_DIM + lk;
  const float* Wp = W + (size_t)bk * N + col0 + bn;
  float acc[4][4] = {{0.f, 0.f, 0.f, 0.f}, {0.f, 0.f, 0.f, 0.f},
                     {0.f, 0.f, 0.f, 0.f}, {0.f, 0.f, 0.f, 0.f}};
  for (int k0 = 0; k0 < K_DIM; k0 += 16) {
    float4 a4 = *(const float4*)(Ap + k0);
    float4 b4 = *(const float4*)(Wp + (size_t)k0 * N);
    __syncthreads();
    As[lk + 0][lm] = a4.x;
    As[lk + 1][lm] = a4.y;
    As[lk + 2][lm] = a4.z;
    As[lk + 3][lm] = a4.w;
    *(float4*)&Bs[bk][bn] = b4;
    __syncthreads();
#pragma unroll
    for (int kk = 0; kk < 16; ++kk) {
      float a0 = As[kk][ty4 + 0];
      float a1 = As[kk][ty4 + 1];
      float a2 = As[kk][ty4 + 2];
      float a3 = As[kk][ty4 + 3];
      float4 b = *(const float4*)&Bs[kk][tx4];
      acc[0][0] = fmaf(a0, b.x, acc[0][0]);
      acc[0][1] = fmaf(a0, b.y, acc[0][1]);
      acc[0][2] = fmaf(a0, b.z, acc[0][2]);
      acc[0][3] = fmaf(a0, b.w, acc[0][3]);
      acc[1][0] = fmaf(a1, b.x, acc[1][0]);
      acc[1][1] = fmaf(a1, b.y, acc[1][1]);
      acc[1][2] = fmaf(a1, b.z, acc[1][2]);
      acc[1][3] = fmaf(a1, b.w, acc[1][3]);
      acc[2][0] = fmaf(a2, b.x, acc[2][0]);
      acc[2][1] = fmaf(a2, b.y, acc[2][1]);
      acc[2][2] = fmaf(a2, b.z, acc[2][2]);
      acc[2][3] = fmaf(a2, b.w, acc[2][3]);
      acc[3][0] = fmaf(a3, b.x, acc[3][0]);
      acc[3][1] = fmaf(a3, b.y, acc[3][1]);
      acc[3][2] = fmaf(a3, b.z, acc[3][2]);
      acc[3][3] = fmaf(a3, b.w, acc[3][3]);
    }
  }
#pragma unroll
  for (int i = 0; i < 4; ++i) {
    int rr = row0 + ty4 + i;
    int b_idx = rr / D;
    int u = rr - b_idx * D;
#pragma unroll
    for (int j = 0; j < 4; ++j) {
      int c = col0 + tx4 + j;
      float v = acc[i][j];
      if (MODE == 0) {
        out[(size_t)b_idx * Dn * N + c] = tanhf(bias[c] + v);
      } else if (MODE == 1) {
        float bc = bias[c];
        out[((size_t)b_idx * Dn + 1 + 2 * u) * N + c] = tanhf(bc - v);
        out[((size_t)b_idx * Dn + 2 + 2 * u) * N + c] = tanhf(bc + v);
      } else {
        out[(size_t)rr * N + c] = v;
      }
    }
  }
}

// Zero-class row: C[b][0][:] = tanh(bias) for every b. (All zero paths of a
// layer share pre-activation == bias.)
__global__ void __launch_bounds__(256)
zero_class_k(float* __restrict__ C, const float* __restrict__ bias, int Dn,
             int N) {
  int i = blockIdx.x * 256 + threadIdx.x;  // over B*N
  int b = i / N, o = i - b * N;
  C[(size_t)b * Dn * N + o] = tanhf(bias[o]);
}

// Row sum-of-squares (monotone in the norm; ties identical). Fixed reduction
// order so identical rows give bitwise-identical keys.
__global__ void __launch_bounds__(256)
rownorm_k(const float* __restrict__ X, float* __restrict__ ns, int N) {
  int row = blockIdx.x;
  int t = threadIdx.x;
  const float* x = X + (size_t)row * N;
  float s = 0.f;
  for (int o = t; o < N; o += 256) {
    float v = x[o];
    s = fmaf(v, v, s);
  }
  __shared__ float red[256];
  red[t] = s;
  __syncthreads();
  for (int off = 128; off; off >>= 1) {
    if (t < off) red[t] += red[t + off];
    __syncthreads();
  }
  if (t == 0) ns[row] = red[0];
}

// Prune after layer 4: 243 expanded entries e = 3*j + t4. Class of path j via
// base-3 digit fold (static structure: no pruning happened before here).
__global__ void __launch_bounds__(256)
prune4_k(const float* __restrict__ ns, int* __restrict__ kept4) {
  int b = blockIdx.x, t = threadIdx.x;
  __shared__ float nss[31];
  __shared__ float key[243];
  __shared__ int cls[243];
  if (t < 31) nss[t] = ns[b * 31 + t];
  __syncthreads();
  if (t < 243) {
    int j = t / 3, t4 = t - 3 * j;
    int d0 = j / 27, d1 = (j / 9) % 3, d2 = (j / 3) % 3, d3 = j % 3;
    int u = 0;
    u = (d0 == 1) ? 0 : (1 + 2 * u + (d0 == 2));
    u = (d1 == 1) ? 0 : (1 + 2 * u + (d1 == 2));
    u = (d2 == 1) ? 0 : (1 + 2 * u + (d2 == 2));
    u = (d3 == 1) ? 0 : (1 + 2 * u + (d3 == 2));
    cls[t] = u;
    key[t] = (t4 == 1) ? 0.f : nss[u];
  }
  __syncthreads();
  if (t < 243) {
    float k = key[t];
    int rank = 0;
    for (int e = 0; e < 243; ++e) {
      float ke = key[e];
      rank += (ke > k) || (ke == k && e < t);
    }
    if (rank < 128) {
      int j = t / 3, t4 = t - 3 * j;
      kept4[b * 128 + rank] = (cls[t] << 1) | (t4 == 2 ? 1 : 0);
    }
  }
}

// Norm keys of the 128 kept layer-5 pre-activations: pos_m = b5 + s*Y5[c].
__global__ void __launch_bounds__(128)
pathnorm_k(const float* __restrict__ Y5, const float* __restrict__ b5,
           const int* __restrict__ kept4, float* __restrict__ pn) {
  int i = blockIdx.x;  // b*128 + m
  int b = i >> 7;
  int k4 = kept4[i];
  int c = k4 >> 1;
  float s = (k4 & 1) ? 1.f : -1.f;
  const float* y = Y5 + ((size_t)b * 31 + c) * 512;
  int t = threadIdx.x;
  float acc = 0.f;
  for (int o = t; o < 512; o += 128) {
    float v = fmaf(s, y[o], b5[o]);
    acc = fmaf(v, v, acc);
  }
  __shared__ float red[128];
  red[t] = acc;
  __syncthreads();
  for (int off = 64; off; off >>= 1) {
    if (t < off) red[t] += red[t + off];
    __syncthreads();
  }
  if (t == 0) pn[i] = red[0];
}

// Final prune: 384 entries e = 3*m + tt.
__global__ void __launch_bounds__(384)
prune5_k(const float* __restrict__ pn, int* __restrict__ kept5) {
  int b = blockIdx.x, t = threadIdx.x;
  __shared__ float pns[128];
  __shared__ float key[384];
  if (t < 128) pns[t] = pn[b * 128 + t];
  __syncthreads();
  int m = t / 3, tt = t - 3 * m;
  key[t] = (tt == 1) ? 0.f : pns[m];
  __syncthreads();
  float k = key[t];
  int rank = 0;
  for (int e = 0; e < 384; ++e) {
    float ke = key[e];
    rank += (ke > k) || (ke == k && e < t);
  }
  if (rank < 128) kept5[b * 128 + rank] = (m << 1) | (tt == 2 ? 1 : 0);
}

// Materialize final data (B,512,128) and argmax-|.| output (B,512).
// data[b,o,r] = sig_r*b5[o] + (sig_r*s4_{m_r})*Y5[b, c_{m_r}, o]
__global__ void __launch_bounds__(128)
finalize_k(const float* __restrict__ Y5, const float* __restrict__ b5,
           const int* __restrict__ kept4, const int* __restrict__ kept5,
           float* __restrict__ out, float* __restrict__ dataout) {
  int b = blockIdx.y;
  int o0 = blockIdx.x * 128;
  __shared__ float Ys[31][129];  // pad: bank = (c + o) % 32, conflict-free
  __shared__ float bias_s[128];
  __shared__ float wav_av[2][128];
  __shared__ float wav_v[2][128];
  __shared__ int wav_r[2][128];
  int t = threadIdx.x;
  for (int c = 0; c < 31; ++c)
    Ys[c][t] = Y5[((size_t)b * 31 + c) * 512 + o0 + t];
  bias_s[t] = b5[o0 + t];
  int k5 = kept5[b * 128 + t];
  int m = k5 >> 1;
  float sig = (k5 & 1) ? 1.f : -1.f;
  int k4 = kept4[b * 128 + m];
  int cc = k4 >> 1;
  float s4 = (k4 & 1) ? 1.f : -1.f;
  float afac = sig * s4;
  __syncthreads();
  int wv = t >> 6, ln = t & 63;
  for (int ol = 0; ol < 128; ++ol) {
    float v = sig * bias_s[ol] + afac * Ys[cc][ol];
    dataout[((size_t)b * 512 + o0 + ol) * 128 + t] = v;
    float av = fabsf(v);
    float vv = v;
    int ridx = t;
    for (int off = 32; off; off >>= 1) {
      float oav = __shfl_down(av, off);
      float ovv = __shfl_down(vv, off);
      int orr = __shfl_down(ridx, off);
      if (oav > av || (oav == av && orr < ridx)) {
        av = oav;
        vv = ovv;
        ridx = orr;
      }
    }
    if (ln == 0) {
      wav_av[wv][ol] = av;
      wav_v[wv][ol] = vv;
      wav_r[wv][ol] = ridx;
    }
  }
  __syncthreads();
  if (t < 128) {
    float a0 = wav_av[0][t], a1 = wav_av[1][t];
    float v = (a1 > a0) ? wav_v[1][t] : wav_v[0][t];  // tie -> wave0 (smaller r)
    out[(size_t)b * 512 + t + o0] = v;
  }
}

extern "C" void kernel_launch(void* const* d_in, const int* in_sizes, int n_in,
                              void* d_out, int out_size, void* d_ws,
                              size_t ws_size, hipStream_t stream) {
  const float* x = (const float*)d_in[0];
  const float* Wts[6];
  const float* bs[6];
  for (int i = 0; i < 6; ++i) {
    Wts[i] = (const float*)d_in[1 + 2 * i];
    bs[i] = (const float*)d_in[2 + 2 * i];
  }
  float* ws = (float*)d_ws;
  float* C1 = ws;                       // B*1*1024
  float* C2 = C1 + 128 * 1 * 1024;      // B*3*1024
  float* C3 = C2 + 128 * 3 * 1024;      // B*7*1024
  float* C4 = C3 + 128 * 7 * 1024;      // B*15*1024
  float* C5 = C4 + 128 * 15 * 1024;     // B*31*1024
  float* Y5 = C5 + 128 * 31 * 1024;     // B*31*512
  float* ns = Y5 + 128 * 31 * 512;      // B*31
  float* pn = ns + 128 * 31;            // B*128
  int* kept4 = (int*)(pn + 128 * 128);  // B*128
  int* kept5 = kept4 + 128 * 128;       // B*128
  float* outp = (float*)d_out;
  float* dataout = outp + 128 * 512;

  dim3 blk(256);
  // Layer 0: x (B,1024) -> C1 (B,1,1024)
  gemm_cls<0><<<dim3(16, 2), blk, 0, stream>>>(x, Wts[0], bs[0], C1, 1, 1, 1024);
  // Layer 1: C1 -> C2 (B,3,1024)
  zero_class_k<<<dim3(512), blk, 0, stream>>>(C2, bs[1], 3, 1024);
  gemm_cls<1><<<dim3(16, 2), blk, 0, stream>>>(C1, Wts[1], bs[1], C2, 1, 3, 1024);
  // Layer 2: C2 -> C3 (B,7,1024)
  zero_class_k<<<dim3(512), blk, 0, stream>>>(C3, bs[2], 7, 1024);
  gemm_cls<1><<<dim3(16, 6), blk, 0, stream>>>(C2, Wts[2], bs[2], C3, 3, 7, 1024);
  // Layer 3: C3 -> C4 (B,15,1024)
  zero_class_k<<<dim3(512), blk, 0, stream>>>(C4, bs[3], 15, 1024);
  gemm_cls<1><<<dim3(16, 14), blk, 0, stream>>>(C3, Wts[3], bs[3], C4, 7, 15, 1024);
  // Layer 4: C4 -> C5 (B,31,1024)
  zero_class_k<<<dim3(512), blk, 0, stream>>>(C5, bs[4], 31, 1024);
  gemm_cls<1><<<dim3(16, 30), blk, 0, stream>>>(C4, Wts[4], bs[4], C5, 15, 31, 1024);
  // Prune 243 -> 128 (keys = per-class sumsq, computed once => exact ties)
  rownorm_k<<<dim3(128 * 31), blk, 0, stream>>>(C5, ns, 1024);
  prune4_k<<<dim3(128), blk, 0, stream>>>(ns, kept4);
  // Layer 5 products: C5 -> Y5 (B,31,512) raw
  gemm_cls<2><<<dim3(8, 62), blk, 0, stream>>>(C5, Wts[5], bs[5], Y5, 31, 0, 512);
  // Final prune 384 -> 128 and output
  pathnorm_k<<<dim3(128 * 128), dim3(128), 0, stream>>>(Y5, bs[5], kept4, pn);
  prune5_k<<<dim3(128), dim3(384), 0, stream>>>(pn, kept5);
  finalize_k<<<dim3(4, 128), dim3(128), 0, stream>>>(Y5, bs[5], kept4, kept5,
                                                     outp, dataout);
}

// Round 2
// 356.330 us; speedup vs baseline: 1.7365x; 1.7365x over previous
//
#include <hip/hip_runtime.h>
#include <math.h>

// PathPreservingNetwork — factored-class implementation, round 2.
// Classes per layer input: 1,1,3,7,15,31. All values are s*C[class], s in
// {-1,0,+1}. Prune ties stay bitwise-exact because every key is computed once
// per (class,sign) and shared by all duplicate paths.

#define KDIM 1024
#define B_SZ 128

__device__ __forceinline__ float4 tanh4(float4 a) {
  return make_float4(tanhf(a.x), tanhf(a.y), tanhf(a.z), tanhf(a.w));
}
__device__ __forceinline__ float4 sub4(float4 a, float4 b) {
  return make_float4(a.x - b.x, a.y - b.y, a.z - b.z, a.w - b.w);
}
__device__ __forceinline__ float4 add4(float4 a, float4 b) {
  return make_float4(a.x + b.x, a.y + b.y, a.z + b.z, a.w + b.w);
}

// ------------------------------------------------------------------ GEMM ----
// Split-K partial GEMM: A (rows x 1024) row-major, W (1024 x N) row-major.
// Block (bx,by,bz): 64x64 output tile over K-chunk [bz*KC, (bz+1)*KC).
// Writes raw partial sums to P[bz][row][col].
__global__ void __launch_bounds__(256)
gemm_part(const float* __restrict__ A, const float* __restrict__ W,
          float* __restrict__ P, int N, int KC) {
  __shared__ float As[32][68];  // [k][m], stride 68 keeps float4 16B-aligned
  __shared__ float Bs[32][68];  // [k][n]
  const int t = threadIdx.x;
  const int tx4 = (t & 15) * 4, ty4 = (t >> 4) * 4;
  const int row0 = blockIdx.y * 64;
  const int col0 = blockIdx.x * 64;
  const int kb = blockIdx.z * KC;
  const int lm = t >> 2, lk8 = (t & 3) * 8;   // A staging
  const int bk = t >> 3, bn8 = (t & 7) * 8;   // B staging
  const float* Ap = A + (size_t)(row0 + lm) * KDIM + kb + lk8;
  const float* Wp = W + (size_t)(kb + bk) * N + col0 + bn8;
  float acc[4][4] = {{0.f, 0.f, 0.f, 0.f}, {0.f, 0.f, 0.f, 0.f},
                     {0.f, 0.f, 0.f, 0.f}, {0.f, 0.f, 0.f, 0.f}};
  for (int k0 = 0; k0 < KC; k0 += 32) {
    float4 a0 = *(const float4*)(Ap + k0);
    float4 a1 = *(const float4*)(Ap + k0 + 4);
    float4 b0 = *(const float4*)(Wp + (size_t)k0 * N);
    float4 b1 = *(const float4*)(Wp + (size_t)k0 * N + 4);
    __syncthreads();
    As[lk8 + 0][lm] = a0.x; As[lk8 + 1][lm] = a0.y;
    As[lk8 + 2][lm] = a0.z; As[lk8 + 3][lm] = a0.w;
    As[lk8 + 4][lm] = a1.x; As[lk8 + 5][lm] = a1.y;
    As[lk8 + 6][lm] = a1.z; As[lk8 + 7][lm] = a1.w;
    *(float4*)&Bs[bk][bn8] = b0;
    *(float4*)&Bs[bk][bn8 + 4] = b1;
    __syncthreads();
#pragma unroll
    for (int kk = 0; kk < 32; ++kk) {
      float4 a = *(const float4*)&As[kk][ty4];
      float4 b = *(const float4*)&Bs[kk][tx4];
      acc[0][0] = fmaf(a.x, b.x, acc[0][0]);
      acc[0][1] = fmaf(a.x, b.y, acc[0][1]);
      acc[0][2] = fmaf(a.x, b.z, acc[0][2]);
      acc[0][3] = fmaf(a.x, b.w, acc[0][3]);
      acc[1][0] = fmaf(a.y, b.x, acc[1][0]);
      acc[1][1] = fmaf(a.y, b.y, acc[1][1]);
      acc[1][2] = fmaf(a.y, b.z, acc[1][2]);
      acc[1][3] = fmaf(a.y, b.w, acc[1][3]);
      acc[2][0] = fmaf(a.z, b.x, acc[2][0]);
      acc[2][1] = fmaf(a.z, b.y, acc[2][1]);
      acc[2][2] = fmaf(a.z, b.z, acc[2][2]);
      acc[2][3] = fmaf(a.z, b.w, acc[2][3]);
      acc[3][0] = fmaf(a.w, b.x, acc[3][0]);
      acc[3][1] = fmaf(a.w, b.y, acc[3][1]);
      acc[3][2] = fmaf(a.w, b.z, acc[3][2]);
      acc[3][3] = fmaf(a.w, b.w, acc[3][3]);
    }
  }
  const size_t R = (size_t)gridDim.y * 64;
#pragma unroll
  for (int i = 0; i < 4; ++i) {
    size_t idx = ((size_t)blockIdx.z * R + row0 + ty4 + i) * N + col0 + tx4;
    *(float4*)&P[idx] = make_float4(acc[i][0], acc[i][1], acc[i][2], acc[i][3]);
  }
}

// Fused GEMM for the big layers (enough blocks).
// MODE 1: out rows (b*Dn+1+2u)=tanh(bias-acc), (b*Dn+2+2u)=tanh(bias+acc)
// MODE 2: out row rr = acc (raw)
template <int MODE>
__global__ void __launch_bounds__(256)
gemm_cls(const float* __restrict__ A, const float* __restrict__ W,
         const float* __restrict__ bias, float* __restrict__ out,
         int D, int Dn, int N) {
  __shared__ float As[32][68];
  __shared__ float Bs[32][68];
  const int t = threadIdx.x;
  const int tx4 = (t & 15) * 4, ty4 = (t >> 4) * 4;
  const int row0 = blockIdx.y * 64;
  const int col0 = blockIdx.x * 64;
  const int lm = t >> 2, lk8 = (t & 3) * 8;
  const int bk = t >> 3, bn8 = (t & 7) * 8;
  const float* Ap = A + (size_t)(row0 + lm) * KDIM + lk8;
  const float* Wp = W + (size_t)bk * N + col0 + bn8;
  float acc[4][4] = {{0.f, 0.f, 0.f, 0.f}, {0.f, 0.f, 0.f, 0.f},
                     {0.f, 0.f, 0.f, 0.f}, {0.f, 0.f, 0.f, 0.f}};
  for (int k0 = 0; k0 < KDIM; k0 += 32) {
    float4 a0 = *(const float4*)(Ap + k0);
    float4 a1 = *(const float4*)(Ap + k0 + 4);
    float4 b0 = *(const float4*)(Wp + (size_t)k0 * N);
    float4 b1 = *(const float4*)(Wp + (size_t)k0 * N + 4);
    __syncthreads();
    As[lk8 + 0][lm] = a0.x; As[lk8 + 1][lm] = a0.y;
    As[lk8 + 2][lm] = a0.z; As[lk8 + 3][lm] = a0.w;
    As[lk8 + 4][lm] = a1.x; As[lk8 + 5][lm] = a1.y;
    As[lk8 + 6][lm] = a1.z; As[lk8 + 7][lm] = a1.w;
    *(float4*)&Bs[bk][bn8] = b0;
    *(float4*)&Bs[bk][bn8 + 4] = b1;
    __syncthreads();
#pragma unroll
    for (int kk = 0; kk < 32; ++kk) {
      float4 a = *(const float4*)&As[kk][ty4];
      float4 b = *(const float4*)&Bs[kk][tx4];
      acc[0][0] = fmaf(a.x, b.x, acc[0][0]);
      acc[0][1] = fmaf(a.x, b.y, acc[0][1]);
      acc[0][2] = fmaf(a.x, b.z, acc[0][2]);
      acc[0][3] = fmaf(a.x, b.w, acc[0][3]);
      acc[1][0] = fmaf(a.y, b.x, acc[1][0]);
      acc[1][1] = fmaf(a.y, b.y, acc[1][1]);
      acc[1][2] = fmaf(a.y, b.z, acc[1][2]);
      acc[1][3] = fmaf(a.y, b.w, acc[1][3]);
      acc[2][0] = fmaf(a.z, b.x, acc[2][0]);
      acc[2][1] = fmaf(a.z, b.y, acc[2][1]);
      acc[2][2] = fmaf(a.z, b.z, acc[2][2]);
      acc[2][3] = fmaf(a.z, b.w, acc[2][3]);
      acc[3][0] = fmaf(a.w, b.x, acc[3][0]);
      acc[3][1] = fmaf(a.w, b.y, acc[3][1]);
      acc[3][2] = fmaf(a.w, b.z, acc[3][2]);
      acc[3][3] = fmaf(a.w, b.w, acc[3][3]);
    }
  }
#pragma unroll
  for (int i = 0; i < 4; ++i) {
    int rr = row0 + ty4 + i;
    float4 v = make_float4(acc[i][0], acc[i][1], acc[i][2], acc[i][3]);
    if (MODE == 1) {
      int b = rr / D, u = rr - b * D;
      float4 bc = *(const float4*)(bias + col0 + tx4);
      *(float4*)&out[((size_t)b * Dn + 1 + 2 * u) * N + col0 + tx4] =
          tanh4(sub4(bc, v));
      *(float4*)&out[((size_t)b * Dn + 2 + 2 * u) * N + col0 + tx4] =
          tanh4(add4(bc, v));
    } else {
      *(float4*)&out[(size_t)rr * N + col0 + tx4] = v;
    }
  }
}

// Combine split-K partials for layer 0: C1[b][c] = tanh(b0[c] + sum_ks P).
__global__ void __launch_bounds__(256)
comb0_k(const float* __restrict__ P, const float* __restrict__ bias,
        float* __restrict__ out, int KS, int R, int N) {
  int i = blockIdx.x * 256 + threadIdx.x;  // over R*N/4
  int n4 = N >> 2;
  int r = i / n4, c4 = (i - r * n4) * 4;
  float4 y = *(const float4*)&P[(size_t)r * N + c4];
  size_t stride = (size_t)R * N;
  for (int ks = 1; ks < KS; ++ks) {
    float4 p = *(const float4*)&P[ks * stride + (size_t)r * N + c4];
    y = add4(y, p);
  }
  float4 bc = *(const float4*)(bias + c4);
  *(float4*)&out[(size_t)r * N + c4] = tanh4(add4(bc, y));
}

// Combine split-K partials for layers 1..3 (MODE1 epilogue + zero row fused).
__global__ void __launch_bounds__(256)
comb1_k(const float* __restrict__ P, const float* __restrict__ bias,
        float* __restrict__ out, int KS, int R, int N, int D, int Dn) {
  int i = blockIdx.x * 256 + threadIdx.x;  // over R*N/4
  int n4 = N >> 2;
  int r = i / n4, c4 = (i - r * n4) * 4;
  int b = r / D, u = r - b * D;
  float4 y = *(const float4*)&P[(size_t)r * N + c4];
  size_t stride = (size_t)R * N;
  for (int ks = 1; ks < KS; ++ks) {
    float4 p = *(const float4*)&P[ks * stride + (size_t)r * N + c4];
    y = add4(y, p);
  }
  float4 bc = *(const float4*)(bias + c4);
  *(float4*)&out[((size_t)b * Dn + 1 + 2 * u) * N + c4] = tanh4(sub4(bc, y));
  *(float4*)&out[((size_t)b * Dn + 2 + 2 * u) * N + c4] = tanh4(add4(bc, y));
  if (u == 0) *(float4*)&out[(size_t)b * Dn * N + c4] = tanh4(bc);
}

// Zero-class row for C5: C[b][0][:] = tanh(bias).
__global__ void __launch_bounds__(256)
zero_class_k(float* __restrict__ C, const float* __restrict__ bias, int Dn,
             int N) {
  int i = blockIdx.x * 256 + threadIdx.x;  // over B*N
  int b = i / N, o = i - b * N;
  C[(size_t)b * Dn * N + o] = tanhf(bias[o]);
}

// Row sum-of-squares of C5 classes (fixed order -> exact duplicate ties).
__global__ void __launch_bounds__(256)
rownorm_k(const float* __restrict__ X, float* __restrict__ ns, int N) {
  int row = blockIdx.x;
  int t = threadIdx.x;
  const float* x = X + (size_t)row * N;
  float s = 0.f;
  for (int o = t; o < N; o += 256) {
    float v = x[o];
    s = fmaf(v, v, s);
  }
  __shared__ float red[256];
  red[t] = s;
  __syncthreads();
  for (int off = 128; off; off >>= 1) {
    if (t < off) red[t] += red[t + off];
    __syncthreads();
  }
  if (t == 0) ns[row] = red[0];
}

// Prune after layer 4: 243 entries e = 3*j + t4; class via base-3 digit fold.
__global__ void __launch_bounds__(256)
prune4_k(const float* __restrict__ ns, int* __restrict__ kept4) {
  int b = blockIdx.x, t = threadIdx.x;
  __shared__ float nss[31];
  __shared__ float key[243];
  __shared__ int cls[243];
  if (t < 31) nss[t] = ns[b * 31 + t];
  __syncthreads();
  if (t < 243) {
    int j = t / 3, t4 = t - 3 * j;
    int d0 = j / 27, d1 = (j / 9) % 3, d2 = (j / 3) % 3, d3 = j % 3;
    int u = 0;
    u = (d0 == 1) ? 0 : (1 + 2 * u + (d0 == 2));
    u = (d1 == 1) ? 0 : (1 + 2 * u + (d1 == 2));
    u = (d2 == 1) ? 0 : (1 + 2 * u + (d2 == 2));
    u = (d3 == 1) ? 0 : (1 + 2 * u + (d3 == 2));
    cls[t] = u;
    key[t] = (t4 == 1) ? 0.f : nss[u];
  }
  __syncthreads();
  if (t < 243) {
    float k = key[t];
    int rank = 0;
    for (int e = 0; e < 243; ++e) {
      float ke = key[e];
      rank += (ke > k) || (ke == k && e < t);
    }
    if (rank < 128) {
      int t4 = t - 3 * (t / 3);
      kept4[b * 128 + rank] = (cls[t] << 1) | (t4 == 2 ? 1 : 0);
    }
  }
}

// Per-class stats of Y5 rows: dot(b5,Y), ||Y||^2; block 3968 computes ||b5||^2.
__global__ void __launch_bounds__(256)
stats5_k(const float* __restrict__ Y5, const float* __restrict__ b5,
         float* __restrict__ dotv, float* __restrict__ nrmv,
         float* __restrict__ nb5) {
  int row = blockIdx.x;
  int t = threadIdx.x;
  __shared__ float rd[256], rn[256];
  if (row < 3968) {
    const float* y = Y5 + (size_t)row * 512;
    float d = 0.f, n2 = 0.f;
    for (int o = t; o < 512; o += 256) {
      float v = y[o];
      d = fmaf(b5[o], v, d);
      n2 = fmaf(v, v, n2);
    }
    rd[t] = d;
    rn[t] = n2;
    __syncthreads();
    for (int off = 128; off; off >>= 1) {
      if (t < off) {
        rd[t] += rd[t + off];
        rn[t] += rn[t + off];
      }
      __syncthreads();
    }
    if (t == 0) {
      dotv[row] = rd[0];
      nrmv[row] = rn[0];
    }
  } else {
    float n2 = 0.f;
    for (int o = t; o < 512; o += 256) {
      float v = b5[o];
      n2 = fmaf(v, v, n2);
    }
    rn[t] = n2;
    __syncthreads();
    for (int off = 128; off; off >>= 1) {
      if (t < off) rn[t] += rn[t + off];
      __syncthreads();
    }
    if (t == 0) nb5[0] = rn[0];
  }
}

// Final prune 384->128. Key per (class,sign) computed once -> exact ties.
__global__ void __launch_bounds__(384)
prune5_k(const float* __restrict__ dotv, const float* __restrict__ nrmv,
         const float* __restrict__ nb5, const int* __restrict__ kept4,
         int* __restrict__ kept5) {
  int b = blockIdx.x, t = threadIdx.x;
  __shared__ float pns[128];
  __shared__ float key[384];
  if (t < 128) {
    int k4 = kept4[b * 128 + t];
    int c = k4 >> 1;
    float s = (k4 & 1) ? 1.f : -1.f;
    pns[t] = nb5[0] + nrmv[b * 31 + c] + s * 2.f * dotv[b * 31 + c];
  }
  __syncthreads();
  int m = t / 3, tt = t - 3 * m;
  key[t] = (tt == 1) ? 0.f : pns[m];
  __syncthreads();
  float k = key[t];
  int rank = 0;
  for (int e = 0; e < 384; ++e) {
    float ke = key[e];
    rank += (ke > k) || (ke == k && e < t);
  }
  if (rank < 128) kept5[b * 128 + rank] = (m << 1) | (tt == 2 ? 1 : 0);
}

// Final data (B,512,128) + argmax-|.| output (B,512).
// v(b,o,r) = sig_r*b5[o] + (sig_r*s4_r)*Y5[b,c_r,o].
__global__ void __launch_bounds__(256)
finalize_k(const float* __restrict__ Y5, const float* __restrict__ b5,
           const int* __restrict__ kept4, const int* __restrict__ kept5,
           float* __restrict__ out, float* __restrict__ dataout) {
  const int b = blockIdx.y;
  const int o0 = blockIdx.x * 64;
  __shared__ float Ys[31][65];
  __shared__ float bias_s[64];
  __shared__ float vt[64][130];
  __shared__ float ra[64][4];
  __shared__ float rv[64][4];
  const int t = threadIdx.x;
  for (int idx = t; idx < 31 * 64; idx += 256) {
    int c = idx >> 6, o = idx & 63;
    Ys[c][o] = Y5[((size_t)b * 31 + c) * 512 + o0 + o];
  }
  if (t < 64) bias_s[t] = b5[o0 + t];
  const int rr = t & 127, oh = t >> 7;
  int k5 = kept5[b * 128 + rr];
  int m = k5 >> 1;
  float sig = (k5 & 1) ? 1.f : -1.f;
  int k4 = kept4[b * 128 + m];
  int cc = k4 >> 1;
  float s4 = (k4 & 1) ? 1.f : -1.f;
  float afac = sig * s4;
  __syncthreads();
#pragma unroll
  for (int ol = 0; ol < 32; ++ol) {
    int o = oh * 32 + ol;
    float v = sig * bias_s[o] + afac * Ys[cc][o];
    dataout[((size_t)b * 512 + o0 + o) * 128 + rr] = v;
    vt[o][rr] = v;
  }
  __syncthreads();
  // argmax over r per o: thread (o = t>>2, chunk q = t&3) scans 32 ascending.
  int o = t >> 2, q = t & 3;
  float bestv = vt[o][q * 32];
  float besta = fabsf(bestv);
  for (int i = 1; i < 32; ++i) {
    float v = vt[o][q * 32 + i];
    float a = fabsf(v);
    if (a > besta) {  // strict > keeps lowest r in chunk (first occurrence)
      besta = a;
      bestv = v;
    }
  }
  ra[o][q] = besta;
  rv[o][q] = bestv;
  __syncthreads();
  if (t < 64) {
    float ba = ra[t][0], bv = rv[t][0];
#pragma unroll
    for (int qq = 1; qq < 4; ++qq) {
      if (ra[t][qq] > ba) {  // strict > keeps lowest chunk on ties
        ba = ra[t][qq];
        bv = rv[t][qq];
      }
    }
    out[(size_t)b * 512 + o0 + t] = bv;
  }
}

extern "C" void kernel_launch(void* const* d_in, const int* in_sizes, int n_in,
                              void* d_out, int out_size, void* d_ws,
                              size_t ws_size, hipStream_t stream) {
  const float* x = (const float*)d_in[0];
  const float* Wt[6];
  const float* bs[6];
  for (int i = 0; i < 6; ++i) {
    Wt[i] = (const float*)d_in[1 + 2 * i];
    bs[i] = (const float*)d_in[2 + 2 * i];
  }
  float* ws = (float*)d_ws;
  float* C1 = ws;                  // 128*1024
  float* C2 = C1 + 131072;         // 128*3*1024
  float* C3 = C2 + 393216;         // 128*7*1024
  float* C4 = C3 + 917504;         // 128*15*1024
  float* C5 = C4 + 1966080;        // 128*31*1024
  float* Y5 = C5 + 4063232;        // 128*31*512 (P aliases this, lifetime-disjoint)
  float* P = Y5;                   // split-K partials, max 2*896*1024 < 2031616
  float* ns = Y5 + 2031616;        // 3968
  float* dotv = ns + 3968;         // 3968
  float* nrmv = dotv + 3968;       // 3968
  float* nb5 = nrmv + 3968;        // 1
  int* kept4 = (int*)(nb5 + 1);    // 128*128
  int* kept5 = kept4 + 16384;      // 128*128
  float* outp = (float*)d_out;
  float* dataout = outp + B_SZ * 512;

  dim3 blk(256);
  // Layer 0: x -> C1 (split-K 8)
  gemm_part<<<dim3(16, 2, 8), blk, 0, stream>>>(x, Wt[0], P, 1024, 128);
  comb0_k<<<dim3(128), blk, 0, stream>>>(P, bs[0], C1, 8, 128, 1024);
  // Layer 1: C1 -> C2 (split-K 8)
  gemm_part<<<dim3(16, 2, 8), blk, 0, stream>>>(C1, Wt[1], P, 1024, 128);
  comb1_k<<<dim3(128), blk, 0, stream>>>(P, bs[1], C2, 8, 128, 1024, 1, 3);
  // Layer 2: C2 -> C3 (split-K 4)
  gemm_part<<<dim3(16, 6, 4), blk, 0, stream>>>(C2, Wt[2], P, 1024, 256);
  comb1_k<<<dim3(384), blk, 0, stream>>>(P, bs[2], C3, 4, 384, 1024, 3, 7);
  // Layer 3: C3 -> C4 (split-K 2)
  gemm_part<<<dim3(16, 14, 2), blk, 0, stream>>>(C3, Wt[3], P, 1024, 512);
  comb1_k<<<dim3(896), blk, 0, stream>>>(P, bs[3], C4, 2, 896, 1024, 7, 15);
  // Layer 4: C4 -> C5 (fused)
  zero_class_k<<<dim3(512), blk, 0, stream>>>(C5, bs[4], 31, 1024);
  gemm_cls<1><<<dim3(16, 30), blk, 0, stream>>>(C4, Wt[4], bs[4], C5, 15, 31,
                                                1024);
  // Prune 243 -> 128
  rownorm_k<<<dim3(3968), blk, 0, stream>>>(C5, ns, 1024);
  prune4_k<<<dim3(128), blk, 0, stream>>>(ns, kept4);
  // Layer 5 products (raw)
  gemm_cls<2><<<dim3(8, 62), blk, 0, stream>>>(C5, Wt[5], bs[5], Y5, 31, 0,
                                               512);
  // Final prune + output
  stats5_k<<<dim3(3969), blk, 0, stream>>>(Y5, bs[5], dotv, nrmv, nb5);
  prune5_k<<<dim3(128), dim3(384), 0, stream>>>(dotv, nrmv, nb5, kept4, kept5);
  finalize_k<<<dim3(8, 128), blk, 0, stream>>>(Y5, bs[5], kept4, kept5, outp,
                                               dataout);
}